// Round 16
// baseline (211.020 us; speedup 1.0000x reference)
//
#include <hip/hip_runtime.h>
#include <math.h>

#define LR 0.001f

// Sizes
#define B   64
#define IN  2048
#define HID 512
#define OUT 128
#define QC  16          // q-chunks for layer-1 partials
#define GB2 32          // batch-group size for the 2-group L3 pipeline

#define AQ __ATOMIC_ACQUIRE
#define RL __ATOMIC_RELEASE
#define SCP __HIP_MEMORY_SCOPE_AGENT

typedef float vf2 __attribute__((ext_vector_type(2)));
typedef float vf4 __attribute__((ext_vector_type(4)));

// ws layout (floats)
#define WS_ZP    0                       // [B][QC][HID] = 524288
#define WS_ZOP   (WS_ZP + B*QC*HID)      // [B][8][OUT]  = 65536
#define WS_GB    (WS_ZOP + B*8*OUT)      // [B][HID]     = 32768
#define WS_CNT   (WS_GB + B*HID)         // B*16 ints (padded counters)

// out layout (floats)
#define O_L2N   0
#define O_DW0   (B*OUT)
#define O_DB0   (O_DW0 + B*IN*HID)
#define O_DW1   (O_DB0 + B*HID)
#define O_DB1   (O_DW1 + B*HID*OUT)

// ---- layer-1 forward partials for one 32-b group (verbatim r9):
// grid (GB2, QC), block 128; thread owns 4 h (float4), block owns 128 q rows.
__global__ void k_fwd1(const float* __restrict__ x, const float* __restrict__ W0,
                       const float* __restrict__ dW0, float* __restrict__ zp, int bb) {
    const int b = bb + blockIdx.x;
    const int q0 = blockIdx.y * (IN / QC);
    const int h = threadIdx.x * 4;        // 0..508
    const float* xr = x + b * IN;
    float4 acc = make_float4(0.f, 0.f, 0.f, 0.f);
    for (int qi = 0; qi < IN / QC; ++qi) {
        const int q = q0 + qi;
        const float xv = xr[q];
        const float4 w0 = *(const float4*)(W0 + q * HID + h);
        const float4 dw = *(const float4*)(dW0 + ((size_t)(b * IN + q)) * HID + h);
        acc.x += xv * (w0.x + dw.x);
        acc.y += xv * (w0.y + dw.y);
        acc.z += xv * (w0.z + dw.z);
        acc.w += xv * (w0.w + dw.w);
    }
    *(float4*)(zp + (b * QC + blockIdx.y) * HID + h) = acc;
}

// ---- merged middle: fwd2 partial + sibling sync + bwd1, grid (B, 8), block 256.
// Block (b,y) owns h-slab [y*64, y*64+64): tanh stays in LDS; dW1 slab read
// twice within the block (second read L2-hot). Sibling sync via padded
// per-sample counter (all 512 blocks co-resident: capacity 2048).
__global__ __launch_bounds__(256, 4)
void k_mid(const float* __restrict__ zp, const float* __restrict__ bias0,
           const float* __restrict__ db0, const float* __restrict__ W1,
           const float* __restrict__ bias1, const float* __restrict__ db1,
           const float* __restrict__ ut, const float* __restrict__ dW1,
           float* __restrict__ zop, int* __restrict__ cnt,
           float* __restrict__ out_l2n, float* __restrict__ out_db1,
           float* __restrict__ out_dW1, float* __restrict__ out_db0,
           float* __restrict__ gb) {
    const int b = blockIdx.x, y = blockIdx.y, tid = threadIdx.x;
    const int h0 = y * 64;
    __shared__ float sth[64];
    __shared__ float tmp[256];
    __shared__ float sg2[OUT];
    __shared__ float sred[6];

    // tanh for the slab: 64 h x 4 subs, each sub sums 4 of 16 chunks
    {
        const int hl = tid & 63, sub = tid >> 6;
        float zs = 0.f;
        const float* p = zp + (size_t)(b * QC) * HID + h0 + hl;
        #pragma unroll
        for (int k = 0; k < 4; ++k) zs += p[(sub * 4 + k) * HID];
        tmp[sub * 64 + hl] = zs;
    }
    __syncthreads();
    if (tid < 64) {
        const int h = h0 + tid;
        const float z = tmp[tid] + tmp[64 + tid] + tmp[128 + tid] + tmp[192 + tid]
                      + bias0[h] + db0[b * HID + h];
        sth[tid] = tanhf(z);
    }
    __syncthreads();
    // zop partial over the slab: o = tid&127, sub = tid>>7 owns 32 h
    {
        const int o = tid & 127, sub = tid >> 7;
        float acc = 0.f;
        #pragma unroll 4
        for (int k = 0; k < 32; ++k) {
            const int hl = sub * 32 + k;
            const int h = h0 + hl;
            acc += sth[hl] * (W1[h * OUT + o] + dW1[((size_t)b * HID + h) * OUT + o]);
        }
        tmp[sub * 128 + o] = acc;
    }
    __syncthreads();
    if (tid < 128)
        zop[(b * 8 + y) * OUT + tid] = tmp[tid] + tmp[128 + tid];
    __syncthreads();
    __threadfence();
    if (tid == 0) {
        __hip_atomic_fetch_add(&cnt[b * 16], 1, RL, SCP);
        while (__hip_atomic_load(&cnt[b * 16], AQ, SCP) < 8)
            __builtin_amdgcn_s_sleep(2);
    }
    __syncthreads();

    // stats + g2 (tid < 128, two waves)
    if (tid < 128) {
        const int o = tid;
        float zo = bias1[o] + db1[b * OUT + o];
        #pragma unroll
        for (int c = 0; c < 8; ++c) zo += zop[(b * 8 + c) * OUT + o];
        const float tr = ut[b * OUT + o];
        float a = zo * zo, c2 = tr * tr, d = tr * zo;
        for (int off = 32; off; off >>= 1) {
            a  += __shfl_xor(a,  off, 64);
            c2 += __shfl_xor(c2, off, 64);
            d  += __shfl_xor(d,  off, 64);
        }
        const int wv = tid >> 6;
        if ((tid & 63) == 0) { sred[wv*3] = a; sred[wv*3+1] = c2; sred[wv*3+2] = d; }
        sg2[o] = zo;
    }
    __syncthreads();
    const float l2  = sred[0] + sred[3];                 // squared norm (as in source)
    const float ntv = fmaxf(sqrtf(sred[1] + sred[4]), 1e-12f);
    const float tdot = (sred[2] + sred[5]) / ntv;
    const float sc = 2.0f * tdot / (l2 * l2);
    if (tid < 128) {
        const int o = tid;
        const float zo = sg2[o];
        const float tr = ut[b * OUT + o];
        const float g2 = -(tr / ntv) / l2 + sc * zo;
        sg2[o] = g2;
        if (y == 0) {
            out_l2n[b * OUT + o] = zo / l2;
            out_db1[b * OUT + o] = db1[b * OUT + o] - LR * g2;
        }
    }
    __syncthreads();

    // bwd over the slab (r9 shape): 4 waves x 16 h rows, lane owns 2 o.
    // dW1 slab re-read is L2-hot (read 1us ago by this block).
    {
        const int wv = tid >> 6, lane = tid & 63, o2 = lane * 2;
        const float g2x = sg2[o2], g2y = sg2[o2 + 1];
        for (int i = 0; i < 16; ++i) {
            const int hl = wv * 16 + i;
            const int h = h0 + hl;
            const size_t idx = ((size_t)b * HID + h) * OUT + o2;
            const float2 dw = *(const float2*)(dW1 + idx);
            const float2 w1 = *(const float2*)(W1 + h * OUT + o2);
            float part = g2x * (w1.x + dw.x) + g2y * (w1.y + dw.y);
            for (int off = 32; off; off >>= 1) part += __shfl_xor(part, off, 64);
            const float th = sth[hl];
            vf2 nd;
            nd.x = dw.x - LR * th * g2x;
            nd.y = dw.y - LR * th * g2y;
            __builtin_nontemporal_store(nd, (vf2*)(out_dW1 + idx));
            if (lane == 0) {
                const float gbv = (1.f - th * th) * part;
                gb[b * HID + h] = gbv;
                out_db0[b * HID + h] = db0[b * HID + h] - LR * gbv;
            }
        }
    }
}

// ---- group update (verbatim r9): new_d_weights_0 = dW0 - LR * x[b,q] * gb[b,h]
__global__ void k_upd0(const float* __restrict__ dW0, const float* __restrict__ x,
                       const float* __restrict__ gb, float* __restrict__ out_dW0,
                       int bb) {
    const int n4 = GB2 * IN * HID / 4;   // 8,388,608 float4 per group
    const size_t base = (size_t)bb * IN * HID / 4;
    const int stride = gridDim.x * blockDim.x;
    for (int i = blockIdx.x * blockDim.x + threadIdx.x; i < n4; i += stride) {
        const size_t j = base + i;
        const int h4 = i & (HID / 4 - 1);        // 0..127
        const int rest = i >> 7;
        const int q = rest & (IN - 1);
        const int b = bb + (rest >> 11);
        const float4 dw = ((const float4*)dW0)[j];
        const float xv = x[b * IN + q];
        const float4 g = *(const float4*)(gb + b * HID + h4 * 4);
        vf4 o;
        o.x = dw.x - LR * xv * g.x;
        o.y = dw.y - LR * xv * g.y;
        o.z = dw.z - LR * xv * g.z;
        o.w = dw.w - LR * xv * g.w;
        __builtin_nontemporal_store(o, (vf4*)out_dW0 + j);
    }
}

extern "C" void kernel_launch(void* const* d_in, const int* in_sizes, int n_in,
                              void* d_out, int out_size, void* d_ws, size_t ws_size,
                              hipStream_t stream) {
    (void)in_sizes; (void)n_in; (void)out_size; (void)ws_size;
    const float* x   = (const float*)d_in[0];
    const float* ut  = (const float*)d_in[1];
    const float* W0  = (const float*)d_in[2];
    const float* b0  = (const float*)d_in[3];
    const float* W1  = (const float*)d_in[4];
    const float* b1  = (const float*)d_in[5];
    const float* dW0 = (const float*)d_in[6];
    const float* db0 = (const float*)d_in[7];
    const float* dW1 = (const float*)d_in[8];
    const float* db1 = (const float*)d_in[9];

    float* ws  = (float*)d_ws;
    float* out = (float*)d_out;
    int* cnt = (int*)(ws + WS_CNT);

    // zero sibling counters each replay (graph-capturable)
    hipMemsetAsync(cnt, 0, B * 16 * sizeof(int), stream);

    // Group order: read G1 first, G0 second => G0 is MRU when upd0(G0) runs.
    k_fwd1<<<dim3(GB2, QC), 128, 0, stream>>>(x, W0, dW0, ws + WS_ZP, GB2);  // G1
    k_fwd1<<<dim3(GB2, QC), 128, 0, stream>>>(x, W0, dW0, ws + WS_ZP, 0);    // G0
    k_mid<<<dim3(B, 8), 256, 0, stream>>>(ws + WS_ZP, b0, db0, W1, b1, db1, ut, dW1,
                                          ws + WS_ZOP, cnt,
                                          out + O_L2N, out + O_DB1,
                                          out + O_DW1, out + O_DB0, ws + WS_GB);
    k_upd0<<<dim3(4096), 256, 0, stream>>>(dW0, x, ws + WS_GB, out + O_DW0, 0);    // G0
    k_upd0<<<dim3(4096), 256, 0, stream>>>(dW0, x, ws + WS_GB, out + O_DW0, GB2);  // G1
}

// Round 17
// 151.852 us; speedup vs baseline: 1.3896x; 1.3896x over previous
//
#include <hip/hip_runtime.h>
#include <math.h>

#define LR 0.001f

// Sizes
#define B   64
#define IN  2048
#define HID 512
#define OUT 128
#define QC  16          // q-chunks for layer-1 partials
#define GB2 32          // group size: G0 = b 0..31, G1 = b 32..63

typedef float vf2 __attribute__((ext_vector_type(2)));
typedef float vf4 __attribute__((ext_vector_type(4)));

// ws layout (floats)
#define WS_ZP    0                       // [B][QC][HID] = 524288
#define WS_TANH  (WS_ZP + B*QC*HID)      // [B][HID]     = 32768
#define WS_ZOP   (WS_TANH + B*HID)       // [B][8][OUT]  = 65536
#define WS_GB    (WS_ZOP + B*8*OUT)      // [B][HID]     = 32768

// out layout (floats)
#define O_L2N   0
#define O_DW0   (B*OUT)
#define O_DB0   (O_DW0 + B*IN*HID)
#define O_DW1   (O_DB0 + B*HID)
#define O_DB1   (O_DW1 + B*HID*OUT)

// ---- layer-1 forward partials, single launch with G1-first block ordering:
// blocks 0..31 handle b=32..63 (G1), blocks 32..63 handle b=0..31 (G0).
// Dispatch is ~ascending by blockIdx => G0's dW0 slab is MRU in L3 at kernel
// end, ready for k_upd0m's ascending read. Kernel body verbatim r9.
__global__ void k_fwd1m(const float* __restrict__ x, const float* __restrict__ W0,
                        const float* __restrict__ dW0, float* __restrict__ zp) {
    const int b = (blockIdx.x + GB2) & (B - 1);
    const int q0 = blockIdx.y * (IN / QC);
    const int h = threadIdx.x * 4;        // 0..508
    const float* xr = x + b * IN;
    float4 acc = make_float4(0.f, 0.f, 0.f, 0.f);
    for (int qi = 0; qi < IN / QC; ++qi) {
        const int q = q0 + qi;
        const float xv = xr[q];
        const float4 w0 = *(const float4*)(W0 + q * HID + h);
        const float4 dw = *(const float4*)(dW0 + ((size_t)(b * IN + q)) * HID + h);
        acc.x += xv * (w0.x + dw.x);
        acc.y += xv * (w0.y + dw.y);
        acc.z += xv * (w0.z + dw.z);
        acc.w += xv * (w0.w + dw.w);
    }
    *(float4*)(zp + (b * QC + blockIdx.y) * HID + h) = acc;
}

// ---- layer-2 forward (+ fused bias/tanh), verbatim r9:
// grid (B, 8), block 128; block owns 64 h rows, one o per thread.
__global__ void k_fwd2(const float* __restrict__ zp, const float* __restrict__ b0,
                       const float* __restrict__ db0, const float* __restrict__ W1,
                       const float* __restrict__ dW1, float* __restrict__ tanhv,
                       float* __restrict__ zop) {
    const int b = blockIdx.x;
    const int h0 = blockIdx.y * 64;
    const int tid = threadIdx.x;
    __shared__ float sth[64];
    if (tid < 64) {
        const int h = h0 + tid;
        float zsum = 0.f;
        const float* p = zp + (b * QC) * HID + h;
        #pragma unroll
        for (int qc = 0; qc < QC; ++qc) zsum += p[qc * HID];
        const float th = tanhf(zsum + b0[h] + db0[b * HID + h]);
        tanhv[b * HID + h] = th;
        sth[tid] = th;
    }
    __syncthreads();
    const int o = tid;
    float acc = 0.f;
    #pragma unroll 8
    for (int hi = 0; hi < 64; ++hi) {
        const int h = h0 + hi;
        acc += sth[hi] * (W1[h * OUT + o] + dW1[(b * HID + h) * OUT + o]);
    }
    zop[(b * 8 + blockIdx.y) * OUT + o] = acc;
}

// ---- fused middle + backward layer 2, verbatim r9:
// grid (B, 8), block 256 (4 waves); wave owns 16 h rows; lane owns 2 o.
__global__ void k_bwd1(const float* __restrict__ zop, const float* __restrict__ b1,
                       const float* __restrict__ db1, const float* __restrict__ ut,
                       const float* __restrict__ W1, const float* __restrict__ dW1,
                       const float* __restrict__ tanhv, const float* __restrict__ db0,
                       float* __restrict__ out_l2n, float* __restrict__ out_db1,
                       float* __restrict__ out_dW1, float* __restrict__ out_db0,
                       float* __restrict__ gb) {
    const int b = blockIdx.x;
    const int w = threadIdx.x >> 6;
    const int lane = threadIdx.x & 63;
    const int o2 = lane * 2;

    float2 zo;
    zo.x = b1[o2]     + db1[b * OUT + o2];
    zo.y = b1[o2 + 1] + db1[b * OUT + o2 + 1];
    #pragma unroll
    for (int c = 0; c < 8; ++c) {
        const float2 zp2 = *(const float2*)(zop + (b * 8 + c) * OUT + o2);
        zo.x += zp2.x; zo.y += zp2.y;
    }
    const float2 tr = *(const float2*)(ut + b * OUT + o2);
    float a = zo.x * zo.x + zo.y * zo.y;
    float c2 = tr.x * tr.x + tr.y * tr.y;
    float d  = tr.x * zo.x + tr.y * zo.y;
    for (int off = 32; off; off >>= 1) {
        a  += __shfl_xor(a,  off, 64);
        c2 += __shfl_xor(c2, off, 64);
        d  += __shfl_xor(d,  off, 64);
    }
    const float l2 = a;                               // squared norm (as in source)
    const float nt = fmaxf(sqrtf(c2), 1e-12f);        // ||update_target||
    const float tdot = d / nt;                        // sum(t * out2)
    const float s = 2.0f * tdot / (l2 * l2);
    float2 g2;
    g2.x = -(tr.x / nt) / l2 + s * zo.x;
    g2.y = -(tr.y / nt) / l2 + s * zo.y;

    if (blockIdx.y == 0 && w == 0) {
        *(float2*)(out_l2n + b * OUT + o2) = make_float2(zo.x / l2, zo.y / l2);
        *(float2*)(out_db1 + b * OUT + o2) =
            make_float2(db1[b * OUT + o2] - LR * g2.x, db1[b * OUT + o2 + 1] - LR * g2.y);
    }

    for (int i = 0; i < 16; ++i) {
        const int h = blockIdx.y * 64 + w * 16 + i;
        const int idx = (b * HID + h) * OUT + o2;
        const float2 dw = *(const float2*)(dW1 + idx);
        const float2 w1 = *(const float2*)(W1 + h * OUT + o2);
        float part = g2.x * (w1.x + dw.x) + g2.y * (w1.y + dw.y);
        for (int off = 32; off; off >>= 1) part += __shfl_xor(part, off, 64);
        const float th = tanhv[b * HID + h];
        vf2 nd;
        nd.x = dw.x - LR * th * g2.x;
        nd.y = dw.y - LR * th * g2.y;
        __builtin_nontemporal_store(nd, (vf2*)(out_dW1 + idx));
        if (lane == 0) {
            const float gbv = (1.f - th * th) * part;
            gb[b * HID + h] = gbv;
            out_db0[b * HID + h] = db0[b * HID + h] - LR * gbv;
        }
    }
}

// ---- update, single launch, ascending block ordering:
// block i owns float4 chunk [i*2048, (i+1)*2048) — ascending dispatch reads
// G0 (first half, MRU after k_fwd1m) first, G1 remnant second.
// Plain loads (want L3 hits), NT stores (never-reused output stream).
__global__ void k_upd0m(const float* __restrict__ dW0, const float* __restrict__ x,
                        const float* __restrict__ gb, float* __restrict__ out_dW0) {
    const int tid = threadIdx.x;
    const size_t base = (size_t)blockIdx.x * 2048;
    #pragma unroll 8
    for (int it = 0; it < 8; ++it) {
        const size_t j = base + (size_t)it * 256 + tid;
        const int h4 = (int)(j & (HID / 4 - 1));     // 0..127
        const int rest = (int)(j >> 7);
        const int q = rest & (IN - 1);
        const int b = rest >> 11;
        const float4 dw = ((const float4*)dW0)[j];
        const float xv = x[b * IN + q];
        const float4 g = *(const float4*)(gb + b * HID + h4 * 4);
        vf4 o;
        o.x = dw.x - LR * xv * g.x;
        o.y = dw.y - LR * xv * g.y;
        o.z = dw.z - LR * xv * g.z;
        o.w = dw.w - LR * xv * g.w;
        __builtin_nontemporal_store(o, (vf4*)out_dW0 + j);
    }
}

extern "C" void kernel_launch(void* const* d_in, const int* in_sizes, int n_in,
                              void* d_out, int out_size, void* d_ws, size_t ws_size,
                              hipStream_t stream) {
    (void)in_sizes; (void)n_in; (void)out_size; (void)ws_size;
    const float* x   = (const float*)d_in[0];
    const float* ut  = (const float*)d_in[1];
    const float* W0  = (const float*)d_in[2];
    const float* b0  = (const float*)d_in[3];
    const float* W1  = (const float*)d_in[4];
    const float* b1  = (const float*)d_in[5];
    const float* dW0 = (const float*)d_in[6];
    const float* db0 = (const float*)d_in[7];
    const float* dW1 = (const float*)d_in[8];
    const float* db1 = (const float*)d_in[9];

    float* ws  = (float*)d_ws;
    float* out = (float*)d_out;

    k_fwd1m<<<dim3(B, QC), 128, 0, stream>>>(x, W0, dW0, ws + WS_ZP);
    k_fwd2<<<dim3(B, 8), 128, 0, stream>>>(ws + WS_ZP, b0, db0, W1, dW1,
                                           ws + WS_TANH, ws + WS_ZOP);
    k_bwd1<<<dim3(B, 8), 256, 0, stream>>>(ws + WS_ZOP, b1, db1, ut, W1, dW1,
                                           ws + WS_TANH, db0,
                                           out + O_L2N, out + O_DB1,
                                           out + O_DW1, out + O_DB0, ws + WS_GB);
    k_upd0m<<<dim3(8192), 256, 0, stream>>>(dW0, x, ws + WS_GB, out + O_DW0);
}